// Round 1
// baseline (507.550 us; speedup 1.0000x reference)
//
#include <hip/hip_runtime.h>
#include <math.h>

// MultiSimilarityLoss on MI355X.
// S = x x^T recomputed in two fused GEMM passes (x is 4 MB -> L2-resident,
// recompute is compute-bound on the fp32 vector ALU; no fp32 MFMA on CDNA4).
// Pass 1: row-wise min_pos / max_neg (per-column-split partials).
// Pass 2: threshold-gated exp-sums (per-column-split partials).
// Small kernels reduce partials, build per-row loss, masked mean.

namespace {

constexpr int Bsz = 8192;
constexpr int Dd  = 128;
constexpr float EPSv = 0.1f;

constexpr int BM = 128, BN = 128, BK = 32;
constexpr int LDA = BM + 4;                        // padded LDS leading dim (floats)
constexpr int NSPLIT = 16;                         // column splits
constexpr int COLS_PER_SPLIT = Bsz / NSPLIT;       // 512
constexpr int CT_PER_SPLIT = COLS_PER_SPLIT / BN;  // 4 col tiles per split
constexpr int NBLK_M = Bsz / BM;                   // 64 row tiles

// Load a BK x BM tile of x (rows base..base+127, k0..k0+31) into LDS,
// stored k-major transposed: T[k][m].  float4 global loads, coalesced-ish
// (8 threads cover one row's 32-float k-chunk); x is L2-resident anyway.
__device__ inline void load_tile(const float* __restrict__ x, int base, int k0,
                                 float* __restrict__ T, int tid) {
  const int f  = tid & 7;   // float4 slot within 32-float k chunk
  const int m0 = tid >> 3;  // 0..31
  const int k  = 4 * f;
#pragma unroll
  for (int mm = 0; mm < 4; ++mm) {
    const int m = m0 + 32 * mm;
    const float4 v =
        *reinterpret_cast<const float4*>(x + (size_t)(base + m) * Dd + k0 + k);
    T[(k + 0) * LDA + m] = v.x;
    T[(k + 1) * LDA + m] = v.y;
    T[(k + 2) * LDA + m] = v.z;
    T[(k + 3) * LDA + m] = v.w;
  }
}

__global__ __launch_bounds__(256)
void k_pass1(const float* __restrict__ x, const int* __restrict__ y,
             float* __restrict__ pMin, float* __restrict__ pMax) {
  __shared__ float smem[2 * BK * LDA];
  float* As = smem;
  float* Bs = smem + BK * LDA;

  const int tid = threadIdx.x;
  const int tm = tid & 15, tn = tid >> 4;
  const int rowbase = blockIdx.x * BM;
  const int split   = blockIdx.y;
  const int r0 = rowbase + 8 * tm;

  float mn[8], mx[8];
  int yRow[8];
#pragma unroll
  for (int rr = 0; rr < 8; ++rr) {
    mn[rr] = INFINITY;
    mx[rr] = -INFINITY;
    yRow[rr] = y[r0 + rr];
  }

  for (int ct = 0; ct < CT_PER_SPLIT; ++ct) {
    const int colbase = split * COLS_PER_SPLIT + ct * BN;
    float acc[8][8];
#pragma unroll
    for (int a = 0; a < 8; ++a)
#pragma unroll
      for (int b = 0; b < 8; ++b) acc[a][b] = 0.f;

    for (int k0 = 0; k0 < Dd; k0 += BK) {
      __syncthreads();
      load_tile(x, rowbase, k0, As, tid);
      load_tile(x, colbase, k0, Bs, tid);
      __syncthreads();
#pragma unroll 8
      for (int k = 0; k < BK; ++k) {
        const float4 a0 = *reinterpret_cast<const float4*>(&As[k * LDA + 8 * tm]);
        const float4 a1 = *reinterpret_cast<const float4*>(&As[k * LDA + 8 * tm + 4]);
        const float4 b0 = *reinterpret_cast<const float4*>(&Bs[k * LDA + 8 * tn]);
        const float4 b1 = *reinterpret_cast<const float4*>(&Bs[k * LDA + 8 * tn + 4]);
        const float av[8] = {a0.x, a0.y, a0.z, a0.w, a1.x, a1.y, a1.z, a1.w};
        const float bv[8] = {b0.x, b0.y, b0.z, b0.w, b1.x, b1.y, b1.z, b1.w};
#pragma unroll
        for (int rr = 0; rr < 8; ++rr)
#pragma unroll
          for (int cc = 0; cc < 8; ++cc)
            acc[rr][cc] = fmaf(av[rr], bv[cc], acc[rr][cc]);
      }
    }

    int yCol[8];
#pragma unroll
    for (int cc = 0; cc < 8; ++cc) yCol[cc] = y[colbase + 8 * tn + cc];
#pragma unroll
    for (int rr = 0; rr < 8; ++rr) {
      const int i = r0 + rr;
#pragma unroll
      for (int cc = 0; cc < 8; ++cc) {
        const int j = colbase + 8 * tn + cc;
        const float s = acc[rr][cc];
        const bool same = (yRow[rr] == yCol[cc]);
        if (same) {
          if (i != j) mn[rr] = fminf(mn[rr], s);
        } else {
          mx[rr] = fmaxf(mx[rr], s);
        }
      }
    }
  }

  // reduce across tn (16 threads share each row); reuse smem (2048 floats)
  float* red = smem;
  __syncthreads();
#pragma unroll
  for (int rr = 0; rr < 8; ++rr) red[tn * BM + 8 * tm + rr] = mn[rr];
  __syncthreads();
  if (tid < BM) {
    float v = INFINITY;
#pragma unroll
    for (int t = 0; t < 16; ++t) v = fminf(v, red[t * BM + tid]);
    pMin[split * Bsz + rowbase + tid] = v;
  }
  __syncthreads();
#pragma unroll
  for (int rr = 0; rr < 8; ++rr) red[tn * BM + 8 * tm + rr] = mx[rr];
  __syncthreads();
  if (tid < BM) {
    float v = -INFINITY;
#pragma unroll
    for (int t = 0; t < 16; ++t) v = fmaxf(v, red[t * BM + tid]);
    pMax[split * Bsz + rowbase + tid] = v;
  }
}

__global__ void k_thresh(const float* __restrict__ pMin, const float* __restrict__ pMax,
                         float* __restrict__ minpos, float* __restrict__ maxneg,
                         float* __restrict__ accum) {
  const int r = blockIdx.x * blockDim.x + threadIdx.x;
  if (r == 0) { accum[0] = 0.f; accum[1] = 0.f; }  // zero loss accumulators (ws is poisoned)
  if (r < Bsz) {
    float mn = INFINITY, mx = -INFINITY;
#pragma unroll
    for (int s = 0; s < NSPLIT; ++s) {
      mn = fminf(mn, pMin[s * Bsz + r]);
      mx = fmaxf(mx, pMax[s * Bsz + r]);
    }
    minpos[r] = mn;
    maxneg[r] = mx;
  }
}

__global__ __launch_bounds__(256)
void k_pass2(const float* __restrict__ x, const int* __restrict__ y,
             const float* __restrict__ minpos, const float* __restrict__ maxneg,
             float* __restrict__ pPos, float* __restrict__ pNeg) {
  __shared__ float smem[2 * BK * LDA];
  float* As = smem;
  float* Bs = smem + BK * LDA;

  const int tid = threadIdx.x;
  const int tm = tid & 15, tn = tid >> 4;
  const int rowbase = blockIdx.x * BM;
  const int split   = blockIdx.y;
  const int r0 = rowbase + 8 * tm;

  float ps[8], ns[8], rMin[8], rMax[8];
  int yRow[8];
#pragma unroll
  for (int rr = 0; rr < 8; ++rr) {
    ps[rr] = 0.f;
    ns[rr] = 0.f;
    rMin[rr] = minpos[r0 + rr];
    rMax[rr] = maxneg[r0 + rr];
    yRow[rr] = y[r0 + rr];
  }

  for (int ct = 0; ct < CT_PER_SPLIT; ++ct) {
    const int colbase = split * COLS_PER_SPLIT + ct * BN;
    float acc[8][8];
#pragma unroll
    for (int a = 0; a < 8; ++a)
#pragma unroll
      for (int b = 0; b < 8; ++b) acc[a][b] = 0.f;

    for (int k0 = 0; k0 < Dd; k0 += BK) {
      __syncthreads();
      load_tile(x, rowbase, k0, As, tid);
      load_tile(x, colbase, k0, Bs, tid);
      __syncthreads();
#pragma unroll 8
      for (int k = 0; k < BK; ++k) {
        const float4 a0 = *reinterpret_cast<const float4*>(&As[k * LDA + 8 * tm]);
        const float4 a1 = *reinterpret_cast<const float4*>(&As[k * LDA + 8 * tm + 4]);
        const float4 b0 = *reinterpret_cast<const float4*>(&Bs[k * LDA + 8 * tn]);
        const float4 b1 = *reinterpret_cast<const float4*>(&Bs[k * LDA + 8 * tn + 4]);
        const float av[8] = {a0.x, a0.y, a0.z, a0.w, a1.x, a1.y, a1.z, a1.w};
        const float bv[8] = {b0.x, b0.y, b0.z, b0.w, b1.x, b1.y, b1.z, b1.w};
#pragma unroll
        for (int rr = 0; rr < 8; ++rr)
#pragma unroll
          for (int cc = 0; cc < 8; ++cc)
            acc[rr][cc] = fmaf(av[rr], bv[cc], acc[rr][cc]);
      }
    }

    int yCol[8];
#pragma unroll
    for (int cc = 0; cc < 8; ++cc) yCol[cc] = y[colbase + 8 * tn + cc];
#pragma unroll
    for (int rr = 0; rr < 8; ++rr) {
      const int i = r0 + rr;
#pragma unroll
      for (int cc = 0; cc < 8; ++cc) {
        const int j = colbase + 8 * tn + cc;
        const float s = acc[rr][cc];
        const bool same = (yRow[rr] == yCol[cc]);
        // exp(beta*(s-1)) = e^-50 * e^(50 s): accumulate unscaled e^(50 s)
        // (>= e^-50, never flushes to 0, so ns>0 <=> any neg kept). Scale at log1p.
        if (!same) {
          if (s + EPSv > rMin[rr]) ns[rr] += __expf(50.f * s);
        } else if (i != j) {
          if (s - EPSv < rMax[rr]) ps[rr] += __expf(-2.f * s);
        }
      }
    }
  }

  float* red = smem;
  __syncthreads();
#pragma unroll
  for (int rr = 0; rr < 8; ++rr) red[tn * BM + 8 * tm + rr] = ps[rr];
  __syncthreads();
  if (tid < BM) {
    float v = 0.f;
#pragma unroll
    for (int t = 0; t < 16; ++t) v += red[t * BM + tid];
    pPos[split * Bsz + rowbase + tid] = v;
  }
  __syncthreads();
#pragma unroll
  for (int rr = 0; rr < 8; ++rr) red[tn * BM + 8 * tm + rr] = ns[rr];
  __syncthreads();
  if (tid < BM) {
    float v = 0.f;
#pragma unroll
    for (int t = 0; t < 16; ++t) v += red[t * BM + tid];
    pNeg[split * Bsz + rowbase + tid] = v;
  }
}

__global__ __launch_bounds__(256)
void k_rows(const float* __restrict__ pPos, const float* __restrict__ pNeg,
            float* __restrict__ accum) {
  const int r = blockIdx.x * 256 + threadIdx.x;
  float contrib = 0.f, cnt = 0.f;
  {
    float psum = 0.f, nsum = 0.f;
#pragma unroll
    for (int s = 0; s < NSPLIT; ++s) {
      psum += pPos[s * Bsz + r];
      nsum += pNeg[s * Bsz + r];
    }
    if (psum > 0.f && nsum > 0.f) {  // valid: any pos kept && any neg kept
      const float E2   = 7.38905609893065f;        // e^{+alpha*lamda}
      const float EM50 = 1.928749847963918e-22f;   // e^{-beta*lamda}
      contrib = 0.5f * log1pf(psum * E2) + 0.02f * log1pf(nsum * EM50);
      cnt = 1.f;
    }
  }
  __shared__ float sb[256], sc[256];
  sb[threadIdx.x] = contrib;
  sc[threadIdx.x] = cnt;
  __syncthreads();
  for (int off = 128; off > 0; off >>= 1) {
    if (threadIdx.x < off) {
      sb[threadIdx.x] += sb[threadIdx.x + off];
      sc[threadIdx.x] += sc[threadIdx.x + off];
    }
    __syncthreads();
  }
  if (threadIdx.x == 0) {
    atomicAdd(&accum[0], sb[0]);
    atomicAdd(&accum[1], sc[0]);
  }
}

__global__ void k_fin(const float* __restrict__ accum, float* __restrict__ out) {
  if (threadIdx.x == 0 && blockIdx.x == 0)
    out[0] = (accum[1] > 0.f) ? accum[0] / accum[1] : 0.f;
}

}  // namespace

extern "C" void kernel_launch(void* const* d_in, const int* in_sizes, int n_in,
                              void* d_out, int out_size, void* d_ws, size_t ws_size,
                              hipStream_t stream) {
  const float* x = (const float*)d_in[0];
  const int*   y = (const int*)d_in[1];
  float* out = (float*)d_out;

  // workspace layout (floats):
  float* pMin   = (float*)d_ws;              // [NSPLIT][Bsz]
  float* pMax   = pMin + NSPLIT * Bsz;       // [NSPLIT][Bsz]
  float* pPos   = pMax + NSPLIT * Bsz;       // [NSPLIT][Bsz]
  float* pNeg   = pPos + NSPLIT * Bsz;       // [NSPLIT][Bsz]
  float* minpos = pNeg + NSPLIT * Bsz;       // [Bsz]
  float* maxneg = minpos + Bsz;              // [Bsz]
  float* accum  = maxneg + Bsz;              // [2] (sum, n_valid)

  dim3 grid(NBLK_M, NSPLIT), blk(256);
  k_pass1<<<grid, blk, 0, stream>>>(x, y, pMin, pMax);
  k_thresh<<<dim3(Bsz / 256), blk, 0, stream>>>(pMin, pMax, minpos, maxneg, accum);
  k_pass2<<<grid, blk, 0, stream>>>(x, y, minpos, maxneg, pPos, pNeg);
  k_rows<<<dim3(Bsz / 256), blk, 0, stream>>>(pPos, pNeg, accum);
  k_fin<<<1, 64, 0, stream>>>(accum, out);
}

// Round 2
// 248.384 us; speedup vs baseline: 2.0434x; 2.0434x over previous
//
#include <hip/hip_runtime.h>
#include <hip/hip_bf16.h>
#include <math.h>

// MultiSimilarityLoss on MI355X — R2: MFMA path.
// S = x x^T via split-bf16: x = xh + xl (both bf16),
// S ≈ Ah·Bh + Ah·Bl + Al·Bh  (3 bf16 MFMA GEMMs, err ~1e-5 on S).
// Pass 1 (mining min_pos/max_neg) and pass 2 (gated exp-sums) both recompute
// S tiles with the identical MFMA pipeline -> masks are self-consistent.
// m97-recipe: 128x128 tile, 4 waves 2x2, 4x4 16x16x32 MFMA tiles/wave,
// global_load_lds width-16 staging, BK=32, K-loop of 4.

namespace {

constexpr int Bsz = 8192;
constexpr int Dd  = 128;
constexpr float EPSv = 0.1f;

constexpr int BM = 128, BN = 128, BK = 32;
constexpr int NSPLIT = 16;
constexpr int COLS_PER_SPLIT = Bsz / NSPLIT;       // 512
constexpr int CT_PER_SPLIT = COLS_PER_SPLIT / BN;  // 4
constexpr int NBLK_M = Bsz / BM;                   // 64

typedef __attribute__((ext_vector_type(8))) short short8;   // 8 bf16 = 4 VGPRs
typedef __attribute__((ext_vector_type(4))) float float4v;  // MFMA C/D

__device__ inline void async_ld16(const void* g, void* l) {
  __builtin_amdgcn_global_load_lds(
      (const __attribute__((address_space(1))) void*)g,
      (__attribute__((address_space(3))) void*)l, 16, 0, 0);
}

// split x (fp32, L2-normalized rows) into hi/lo bf16 arrays
__global__ __launch_bounds__(256)
void k_split(const float* __restrict__ x, ushort* __restrict__ xh,
             ushort* __restrict__ xl) {
  const int i = (blockIdx.x * 256 + threadIdx.x) * 4;
  const float4 v = *reinterpret_cast<const float4*>(x + i);
  const float f[4] = {v.x, v.y, v.z, v.w};
  ushort4 h, l;
  ushort* hp = &h.x;
  ushort* lp = &l.x;
#pragma unroll
  for (int r = 0; r < 4; ++r) {
    __hip_bfloat16 hb = __float2bfloat16(f[r]);
    float hf = __bfloat162float(hb);
    __hip_bfloat16 lb = __float2bfloat16(f[r] - hf);
    ushort hu, lu;
    __builtin_memcpy(&hu, &hb, 2);
    __builtin_memcpy(&lu, &lb, 2);
    hp[r] = hu;
    lp[r] = lu;
  }
  *reinterpret_cast<ushort4*>(xh + i) = h;
  *reinterpret_cast<ushort4*>(xl + i) = l;
}

// PASS=1: out0/out1 = per-split partial min_pos / max_neg.
// PASS=2: out0/out1 = per-split partial pos_sum / neg_sum (unscaled exps).
template <int PASS>
__global__ __launch_bounds__(256)
void k_gemm(const ushort* __restrict__ xh, const ushort* __restrict__ xl,
            const int* __restrict__ y,
            const float* __restrict__ minpos, const float* __restrict__ maxneg,
            float* __restrict__ out0, float* __restrict__ out1) {
  __shared__ __align__(16) short sA_h[BM * BK];  // 8 KB each
  __shared__ __align__(16) short sA_l[BM * BK];
  __shared__ __align__(16) short sB_h[BM * BK];
  __shared__ __align__(16) short sB_l[BM * BK];
  __shared__ int yA[BM], yB[BN];
  __shared__ float red0[BM][2], red1[BM][2];
  __shared__ float rlo[BM], rhi[BM];

  const int tid  = threadIdx.x;
  const int lane = tid & 63;
  const int wave = tid >> 6;
  const int wm = wave >> 1, wn = wave & 1;       // 2x2 wave grid, 64x64 each
  const int q   = lane >> 4;                     // k-chunk / row-quad
  const int c16 = lane & 15;                     // col within 16-tile
  const int rowbase = blockIdx.x * BM;
  const int split   = blockIdx.y;

  if (tid < BM) {
    yA[tid] = y[rowbase + tid];
    if (PASS == 1) {
      red0[tid][0] = INFINITY;  red0[tid][1] = INFINITY;
      red1[tid][0] = -INFINITY; red1[tid][1] = -INFINITY;
    } else {
      red0[tid][0] = 0.f; red0[tid][1] = 0.f;
      red1[tid][0] = 0.f; red1[tid][1] = 0.f;
      rlo[tid] = minpos[rowbase + tid];
      rhi[tid] = maxneg[rowbase + tid];
    }
  }

  // staging: thread t loads 16B chunks t and t+256 of each 128x32 slab.
  // chunk c -> row m=c>>2, k-chunk kc=c&3; LDS offset c*8 halfs (lane-linear,
  // required by global_load_lds wave-uniform-base + lane*16 semantics).
  const int m0 = tid >> 2, kc = tid & 3;
  const int lo8 = tid * 8;

  for (int ct = 0; ct < CT_PER_SPLIT; ++ct) {
    const int colbase = split * COLS_PER_SPLIT + ct * BN;
    float4v acc[4][4];
#pragma unroll
    for (int mt = 0; mt < 4; ++mt)
#pragma unroll
      for (int nt = 0; nt < 4; ++nt) acc[mt][nt] = 0.f;

    for (int k0 = 0; k0 < Dd; k0 += BK) {
      __syncthreads();
      if (k0 == 0 && tid < BN) yB[tid] = y[colbase + tid];
      {
        const size_t ga  = (size_t)(rowbase + m0) * Dd + k0 + kc * 8;
        const size_t gb  = (size_t)(colbase + m0) * Dd + k0 + kc * 8;
        const size_t ga2 = ga + (size_t)64 * Dd;
        const size_t gb2 = gb + (size_t)64 * Dd;
        async_ld16(xh + ga,  sA_h + lo8);
        async_ld16(xl + ga,  sA_l + lo8);
        async_ld16(xh + gb,  sB_h + lo8);
        async_ld16(xl + gb,  sB_l + lo8);
        async_ld16(xh + ga2, sA_h + lo8 + 2048);
        async_ld16(xl + ga2, sA_l + lo8 + 2048);
        async_ld16(xh + gb2, sB_h + lo8 + 2048);
        async_ld16(xl + gb2, sB_l + lo8 + 2048);
      }
      __syncthreads();

      short8 ah[4], al[4], bh[4], bl[4];
#pragma unroll
      for (int t = 0; t < 4; ++t) {
        const int ra = (wm * 64 + t * 16 + c16) * BK + q * 8;
        const int rb = (wn * 64 + t * 16 + c16) * BK + q * 8;
        ah[t] = *reinterpret_cast<const short8*>(sA_h + ra);
        al[t] = *reinterpret_cast<const short8*>(sA_l + ra);
        bh[t] = *reinterpret_cast<const short8*>(sB_h + rb);
        bl[t] = *reinterpret_cast<const short8*>(sB_l + rb);
      }
#pragma unroll
      for (int mt = 0; mt < 4; ++mt)
#pragma unroll
        for (int nt = 0; nt < 4; ++nt) {
          acc[mt][nt] = __builtin_amdgcn_mfma_f32_16x16x32_bf16(
              ah[mt], bh[nt], acc[mt][nt], 0, 0, 0);
          acc[mt][nt] = __builtin_amdgcn_mfma_f32_16x16x32_bf16(
              ah[mt], bl[nt], acc[mt][nt], 0, 0, 0);
          acc[mt][nt] = __builtin_amdgcn_mfma_f32_16x16x32_bf16(
              al[mt], bh[nt], acc[mt][nt], 0, 0, 0);
        }
    }

    // epilogue: C/D layout col=lane&15, row=(lane>>4)*4+reg  [m89-verified]
#pragma unroll
    for (int mt = 0; mt < 4; ++mt) {
#pragma unroll
      for (int r = 0; r < 4; ++r) {
        const int rloc = wm * 64 + mt * 16 + q * 4 + r;
        const int gi = rowbase + rloc;
        const int yi = yA[rloc];
        if (PASS == 1) {
          float mn = INFINITY, mx = -INFINITY;
#pragma unroll
          for (int nt = 0; nt < 4; ++nt) {
            const int cloc = wn * 64 + nt * 16 + c16;
            const int gj = colbase + cloc;
            const float s = acc[mt][nt][r];
            if (yi == yB[cloc]) {
              if (gi != gj) mn = fminf(mn, s);
            } else {
              mx = fmaxf(mx, s);
            }
          }
#pragma unroll
          for (int d = 1; d < 16; d <<= 1) {
            mn = fminf(mn, __shfl_xor(mn, d, 64));
            mx = fmaxf(mx, __shfl_xor(mx, d, 64));
          }
          if (c16 == 0) {
            red0[rloc][wn] = fminf(red0[rloc][wn], mn);
            red1[rloc][wn] = fmaxf(red1[rloc][wn], mx);
          }
        } else {
          float psum = 0.f, nsum = 0.f;
          const float rmn = rlo[rloc], rmx = rhi[rloc];
#pragma unroll
          for (int nt = 0; nt < 4; ++nt) {
            const int cloc = wn * 64 + nt * 16 + c16;
            const int gj = colbase + cloc;
            const float s = acc[mt][nt][r];
            // exp(beta*(s-1)) = e^-50 * e^(50 s): accumulate unscaled e^(50 s)
            // (>= e^-50, never 0, so nsum>0 <=> any neg kept). Scale at log1p.
            if (yi != yB[cloc]) {
              if (s + EPSv > rmn) nsum += __expf(50.f * s);
            } else if (gi != gj) {
              if (s - EPSv < rmx) psum += __expf(-2.f * s);
            }
          }
#pragma unroll
          for (int d = 1; d < 16; d <<= 1) {
            psum += __shfl_xor(psum, d, 64);
            nsum += __shfl_xor(nsum, d, 64);
          }
          if (c16 == 0) {
            red0[rloc][wn] += psum;
            red1[rloc][wn] += nsum;
          }
        }
      }
    }
  }

  __syncthreads();
  if (tid < BM) {
    const int o = split * Bsz + rowbase + tid;
    if (PASS == 1) {
      out0[o] = fminf(red0[tid][0], red0[tid][1]);
      out1[o] = fmaxf(red1[tid][0], red1[tid][1]);
    } else {
      out0[o] = red0[tid][0] + red0[tid][1];
      out1[o] = red1[tid][0] + red1[tid][1];
    }
  }
}

__global__ void k_thresh(const float* __restrict__ pMin, const float* __restrict__ pMax,
                         float* __restrict__ minpos, float* __restrict__ maxneg,
                         float* __restrict__ accum) {
  const int r = blockIdx.x * blockDim.x + threadIdx.x;
  if (r == 0) { accum[0] = 0.f; accum[1] = 0.f; }  // ws is poisoned 0xAA
  if (r < Bsz) {
    float mn = INFINITY, mx = -INFINITY;
#pragma unroll
    for (int s = 0; s < NSPLIT; ++s) {
      mn = fminf(mn, pMin[s * Bsz + r]);
      mx = fmaxf(mx, pMax[s * Bsz + r]);
    }
    minpos[r] = mn;
    maxneg[r] = mx;
  }
}

__global__ __launch_bounds__(256)
void k_rows(const float* __restrict__ pPos, const float* __restrict__ pNeg,
            float* __restrict__ accum) {
  const int r = blockIdx.x * 256 + threadIdx.x;
  float contrib = 0.f, cnt = 0.f;
  {
    float psum = 0.f, nsum = 0.f;
#pragma unroll
    for (int s = 0; s < NSPLIT; ++s) {
      psum += pPos[s * Bsz + r];
      nsum += pNeg[s * Bsz + r];
    }
    if (psum > 0.f && nsum > 0.f) {
      const float E2   = 7.38905609893065f;       // e^{+alpha*lamda}
      const float EM50 = 1.928749847963918e-22f;  // e^{-beta*lamda}
      contrib = 0.5f * log1pf(psum * E2) + 0.02f * log1pf(nsum * EM50);
      cnt = 1.f;
    }
  }
  __shared__ float sb[256], sc[256];
  sb[threadIdx.x] = contrib;
  sc[threadIdx.x] = cnt;
  __syncthreads();
  for (int off = 128; off > 0; off >>= 1) {
    if (threadIdx.x < off) {
      sb[threadIdx.x] += sb[threadIdx.x + off];
      sc[threadIdx.x] += sc[threadIdx.x + off];
    }
    __syncthreads();
  }
  if (threadIdx.x == 0) {
    atomicAdd(&accum[0], sb[0]);
    atomicAdd(&accum[1], sc[0]);
  }
}

__global__ void k_fin(const float* __restrict__ accum, float* __restrict__ out) {
  if (threadIdx.x == 0 && blockIdx.x == 0)
    out[0] = (accum[1] > 0.f) ? accum[0] / accum[1] : 0.f;
}

}  // namespace

extern "C" void kernel_launch(void* const* d_in, const int* in_sizes, int n_in,
                              void* d_out, int out_size, void* d_ws, size_t ws_size,
                              hipStream_t stream) {
  const float* x = (const float*)d_in[0];
  const int*   y = (const int*)d_in[1];
  float* out = (float*)d_out;

  // workspace layout
  ushort* xh = (ushort*)d_ws;                       // [Bsz*Dd] bf16 hi (2 MB)
  ushort* xl = xh + (size_t)Bsz * Dd;               // [Bsz*Dd] bf16 lo (2 MB)
  float* pMin   = (float*)(xl + (size_t)Bsz * Dd);  // [NSPLIT][Bsz]
  float* pMax   = pMin + NSPLIT * Bsz;
  float* pPos   = pMax + NSPLIT * Bsz;
  float* pNeg   = pPos + NSPLIT * Bsz;
  float* minpos = pNeg + NSPLIT * Bsz;              // [Bsz]
  float* maxneg = minpos + Bsz;                     // [Bsz]
  float* accum  = maxneg + Bsz;                     // [2]

  dim3 blk(256);
  k_split<<<dim3((Bsz * Dd) / (256 * 4)), blk, 0, stream>>>(x, xh, xl);

  dim3 grid(NBLK_M, NSPLIT);
  k_gemm<1><<<grid, blk, 0, stream>>>(xh, xl, y, nullptr, nullptr, pMin, pMax);
  k_thresh<<<dim3(Bsz / 256), blk, 0, stream>>>(pMin, pMax, minpos, maxneg, accum);
  k_gemm<2><<<grid, blk, 0, stream>>>(xh, xl, y, minpos, maxneg, pPos, pNeg);
  k_rows<<<dim3(Bsz / 256), blk, 0, stream>>>(pPos, pNeg, accum);
  k_fin<<<1, 64, 0, stream>>>(accum, out);
}

// Round 3
// 183.894 us; speedup vs baseline: 2.7600x; 1.3507x over previous
//
#include <hip/hip_runtime.h>
#include <hip/hip_bf16.h>
#include <math.h>

// MultiSimilarityLoss on MI355X — R3: single pure-bf16 MFMA GEMM per pass.
// Numerics: bf16(x) gives δ(S) RMS ≈ 2.4e-4; loss error ≈ e^{50δ} on neg
// terms → ~2e-4 on the scalar loss (threshold 4.75e-2). Masks consistent:
// both passes recompute the IDENTICAL bf16 S. Boundary mask flips carry
// e^{-29}-relative weight (see R2->R3 analysis).
// Structure: 128x128 block tile, 4 waves 2x2, 4x4 16x16x32 bf16 MFMA/wave,
// global_load_lds width-16 staging (lane-linear LDS, verified R2),
// min/max / psum/nsum carried in registers across the 4 column tiles,
// one shuffle-reduce per block. __launch_bounds__(256,3) for 3 blocks/CU.

namespace {

constexpr int Bsz = 8192;
constexpr int Dd  = 128;
constexpr float EPSv = 0.1f;

constexpr int BM = 128, BN = 128, BK = 32;
constexpr int NSPLIT = 16;
constexpr int COLS_PER_SPLIT = Bsz / NSPLIT;       // 512
constexpr int CT_PER_SPLIT = COLS_PER_SPLIT / BN;  // 4
constexpr int NBLK_M = Bsz / BM;                   // 64

typedef __attribute__((ext_vector_type(8))) short short8;   // 8 bf16 = 4 VGPRs
typedef __attribute__((ext_vector_type(4))) float float4v;  // MFMA C/D

__device__ inline void async_ld16(const void* g, void* l) {
  __builtin_amdgcn_global_load_lds(
      (const __attribute__((address_space(1))) void*)g,
      (__attribute__((address_space(3))) void*)l, 16, 0, 0);
}

// cast x (fp32) to bf16 (round-to-nearest via __float2bfloat16)
__global__ __launch_bounds__(256)
void k_split(const float* __restrict__ x, ushort* __restrict__ xh) {
  const int i = (blockIdx.x * 256 + threadIdx.x) * 4;
  const float4 v = *reinterpret_cast<const float4*>(x + i);
  const float f[4] = {v.x, v.y, v.z, v.w};
  ushort4 h;
  ushort* hp = &h.x;
#pragma unroll
  for (int r = 0; r < 4; ++r) {
    __hip_bfloat16 hb = __float2bfloat16(f[r]);
    ushort hu;
    __builtin_memcpy(&hu, &hb, 2);
    hp[r] = hu;
  }
  *reinterpret_cast<ushort4*>(xh + i) = h;
}

// PASS=1: out0/out1 = per-split partial min_pos / max_neg.
// PASS=2: out0/out1 = per-split partial pos_sum / neg_sum (unscaled exps).
template <int PASS>
__global__ __launch_bounds__(256, 3)
void k_gemm(const ushort* __restrict__ xh, const int* __restrict__ y,
            const float* __restrict__ minpos, const float* __restrict__ maxneg,
            float* __restrict__ out0, float* __restrict__ out1) {
  __shared__ __align__(16) short sA[BM * BK];  // 8 KB
  __shared__ __align__(16) short sB[BM * BK];  // 8 KB
  __shared__ int yA[BM], yB[BN];
  __shared__ float red0[BM][2], red1[BM][2];
  __shared__ float rlo[BM], rhi[BM];

  const int tid  = threadIdx.x;
  const int lane = tid & 63;
  const int wave = tid >> 6;
  const int wm = wave >> 1, wn = wave & 1;  // 2x2 wave grid, 64x64 each
  const int q   = lane >> 4;                // row-quad / k-chunk selector
  const int c16 = lane & 15;                // col within 16-tile
  const int rowbase = blockIdx.x * BM;
  const int split   = blockIdx.y;

  if (tid < BM) {
    yA[tid] = y[rowbase + tid];
    if (PASS == 2) {
      rlo[tid] = minpos[rowbase + tid];
      rhi[tid] = maxneg[rowbase + tid];
    }
  }

  // register carries across all column tiles
  float a0[4][4], a1[4][4];  // PASS1: mn/mx ; PASS2: psum/nsum
#pragma unroll
  for (int mt = 0; mt < 4; ++mt)
#pragma unroll
    for (int r = 0; r < 4; ++r) {
      a0[mt][r] = (PASS == 1) ? INFINITY : 0.f;
      a1[mt][r] = (PASS == 1) ? -INFINITY : 0.f;
    }

  // staging: thread t loads 16B chunks t and t+256 of each 128x32 slab.
  // LDS offset t*8 halfs — lane-linear (global_load_lds wave-uniform base).
  const int m0 = tid >> 2, kc = tid & 3;
  const int lo8 = tid * 8;

  for (int ct = 0; ct < CT_PER_SPLIT; ++ct) {
    const int colbase = split * COLS_PER_SPLIT + ct * BN;
    float4v acc[4][4];
#pragma unroll
    for (int mt = 0; mt < 4; ++mt)
#pragma unroll
      for (int nt = 0; nt < 4; ++nt) acc[mt][nt] = 0.f;

    for (int k0 = 0; k0 < Dd; k0 += BK) {
      __syncthreads();  // also orders prev epilogue's yB reads vs next write
      if (k0 == 0 && tid < BN) yB[tid] = y[colbase + tid];
      {
        const size_t ga  = (size_t)(rowbase + m0) * Dd + k0 + kc * 8;
        const size_t gb  = (size_t)(colbase + m0) * Dd + k0 + kc * 8;
        async_ld16(xh + ga, sA + lo8);
        async_ld16(xh + gb, sB + lo8);
        async_ld16(xh + ga + (size_t)64 * Dd, sA + lo8 + 2048);
        async_ld16(xh + gb + (size_t)64 * Dd, sB + lo8 + 2048);
      }
      __syncthreads();

      short8 ah[4], bh[4];
#pragma unroll
      for (int t = 0; t < 4; ++t) {
        ah[t] = *reinterpret_cast<const short8*>(
            sA + (wm * 64 + t * 16 + c16) * BK + q * 8);
        bh[t] = *reinterpret_cast<const short8*>(
            sB + (wn * 64 + t * 16 + c16) * BK + q * 8);
      }
#pragma unroll
      for (int mt = 0; mt < 4; ++mt)
#pragma unroll
        for (int nt = 0; nt < 4; ++nt)
          acc[mt][nt] = __builtin_amdgcn_mfma_f32_16x16x32_bf16(
              ah[mt], bh[nt], acc[mt][nt], 0, 0, 0);
    }

    // epilogue: C/D layout col=lane&15, row=(lane>>4)*4+reg  [m89-verified,
    // end-to-end validated in R2 with absmax 0.0]
#pragma unroll
    for (int mt = 0; mt < 4; ++mt) {
#pragma unroll
      for (int r = 0; r < 4; ++r) {
        const int rloc = wm * 64 + mt * 16 + q * 4 + r;
        const int gi = rowbase + rloc;
        const int yi = yA[rloc];
        if (PASS == 1) {
          float mn = a0[mt][r], mx = a1[mt][r];
#pragma unroll
          for (int nt = 0; nt < 4; ++nt) {
            const int cloc = wn * 64 + nt * 16 + c16;
            const int gj = colbase + cloc;
            const float s = acc[mt][nt][r];
            if (yi == yB[cloc]) {
              if (gi != gj) mn = fminf(mn, s);
            } else {
              mx = fmaxf(mx, s);
            }
          }
          a0[mt][r] = mn;
          a1[mt][r] = mx;
        } else {
          float psum = a0[mt][r], nsum = a1[mt][r];
          const float rmn = rlo[rloc], rmx = rhi[rloc];
#pragma unroll
          for (int nt = 0; nt < 4; ++nt) {
            const int cloc = wn * 64 + nt * 16 + c16;
            const int gj = colbase + cloc;
            const float s = acc[mt][nt][r];
            // exp(beta*(s-1)) = e^-50 * e^(50 s): accumulate unscaled
            // e^(50 s) (>= e^-50, never 0 -> nsum>0 <=> any neg kept).
            if (yi != yB[cloc]) {
              if (s + EPSv > rmn) nsum += __expf(50.f * s);
            } else if (gi != gj) {
              if (s - EPSv < rmx) psum += __expf(-2.f * s);
            }
          }
          a0[mt][r] = psum;
          a1[mt][r] = nsum;
        }
      }
    }
  }

  // single cross-lane reduce at block end; (rloc, wn) has a unique writer
#pragma unroll
  for (int mt = 0; mt < 4; ++mt) {
#pragma unroll
    for (int r = 0; r < 4; ++r) {
      float v0 = a0[mt][r], v1 = a1[mt][r];
#pragma unroll
      for (int d = 1; d < 16; d <<= 1) {
        if (PASS == 1) {
          v0 = fminf(v0, __shfl_xor(v0, d, 64));
          v1 = fmaxf(v1, __shfl_xor(v1, d, 64));
        } else {
          v0 += __shfl_xor(v0, d, 64);
          v1 += __shfl_xor(v1, d, 64);
        }
      }
      if (c16 == 0) {
        const int rloc = wm * 64 + mt * 16 + q * 4 + r;
        red0[rloc][wn] = v0;
        red1[rloc][wn] = v1;
      }
    }
  }

  __syncthreads();
  if (tid < BM) {
    const int o = split * Bsz + rowbase + tid;
    if (PASS == 1) {
      out0[o] = fminf(red0[tid][0], red0[tid][1]);
      out1[o] = fmaxf(red1[tid][0], red1[tid][1]);
    } else {
      out0[o] = red0[tid][0] + red0[tid][1];
      out1[o] = red1[tid][0] + red1[tid][1];
    }
  }
}

__global__ void k_thresh(const float* __restrict__ pMin, const float* __restrict__ pMax,
                         float* __restrict__ minpos, float* __restrict__ maxneg,
                         float* __restrict__ accum) {
  const int r = blockIdx.x * blockDim.x + threadIdx.x;
  if (r == 0) { accum[0] = 0.f; accum[1] = 0.f; }  // ws is poisoned 0xAA
  if (r < Bsz) {
    float mn = INFINITY, mx = -INFINITY;
#pragma unroll
    for (int s = 0; s < NSPLIT; ++s) {
      mn = fminf(mn, pMin[s * Bsz + r]);
      mx = fmaxf(mx, pMax[s * Bsz + r]);
    }
    minpos[r] = mn;
    maxneg[r] = mx;
  }
}

__global__ __launch_bounds__(256)
void k_rows(const float* __restrict__ pPos, const float* __restrict__ pNeg,
            float* __restrict__ accum) {
  const int r = blockIdx.x * 256 + threadIdx.x;
  float contrib = 0.f, cnt = 0.f;
  {
    float psum = 0.f, nsum = 0.f;
#pragma unroll
    for (int s = 0; s < NSPLIT; ++s) {
      psum += pPos[s * Bsz + r];
      nsum += pNeg[s * Bsz + r];
    }
    if (psum > 0.f && nsum > 0.f) {
      const float E2   = 7.38905609893065f;       // e^{+alpha*lamda}
      const float EM50 = 1.928749847963918e-22f;  // e^{-beta*lamda}
      contrib = 0.5f * log1pf(psum * E2) + 0.02f * log1pf(nsum * EM50);
      cnt = 1.f;
    }
  }
  __shared__ float sb[256], sc[256];
  sb[threadIdx.x] = contrib;
  sc[threadIdx.x] = cnt;
  __syncthreads();
  for (int off = 128; off > 0; off >>= 1) {
    if (threadIdx.x < off) {
      sb[threadIdx.x] += sb[threadIdx.x + off];
      sc[threadIdx.x] += sc[threadIdx.x + off];
    }
    __syncthreads();
  }
  if (threadIdx.x == 0) {
    atomicAdd(&accum[0], sb[0]);
    atomicAdd(&accum[1], sc[0]);
  }
}

__global__ void k_fin(const float* __restrict__ accum, float* __restrict__ out) {
  if (threadIdx.x == 0 && blockIdx.x == 0)
    out[0] = (accum[1] > 0.f) ? accum[0] / accum[1] : 0.f;
}

}  // namespace

extern "C" void kernel_launch(void* const* d_in, const int* in_sizes, int n_in,
                              void* d_out, int out_size, void* d_ws, size_t ws_size,
                              hipStream_t stream) {
  const float* x = (const float*)d_in[0];
  const int*   y = (const int*)d_in[1];
  float* out = (float*)d_out;

  // workspace layout
  ushort* xh = (ushort*)d_ws;                       // [Bsz*Dd] bf16 (2 MB)
  float* pMin   = (float*)(xh + (size_t)Bsz * Dd);  // [NSPLIT][Bsz]
  float* pMax   = pMin + NSPLIT * Bsz;
  float* pPos   = pMax + NSPLIT * Bsz;
  float* pNeg   = pPos + NSPLIT * Bsz;
  float* minpos = pNeg + NSPLIT * Bsz;              // [Bsz]
  float* maxneg = minpos + Bsz;                     // [Bsz]
  float* accum  = maxneg + Bsz;                     // [2]

  dim3 blk(256);
  k_split<<<dim3((Bsz * Dd) / (256 * 4)), blk, 0, stream>>>(x, xh);

  dim3 grid(NBLK_M, NSPLIT);
  k_gemm<1><<<grid, blk, 0, stream>>>(xh, y, nullptr, nullptr, pMin, pMax);
  k_thresh<<<dim3(Bsz / 256), blk, 0, stream>>>(pMin, pMax, minpos, maxneg, accum);
  k_gemm<2><<<grid, blk, 0, stream>>>(xh, y, minpos, maxneg, pPos, pNeg);
  k_rows<<<dim3(Bsz / 256), blk, 0, stream>>>(pPos, pNeg, accum);
  k_fin<<<1, 64, 0, stream>>>(accum, out);
}

// Round 4
// 129.123 us; speedup vs baseline: 3.9308x; 1.4242x over previous
//
#include <hip/hip_runtime.h>
#include <hip/hip_bf16.h>
#include <math.h>

// MultiSimilarityLoss on MI355X — R4: one-shot K (no K-loop staging).
// D=128 = full reduction dim: stage whole 128x128 bf16 slabs (A once/block,
// B once/column-tile), 64 MFMA per wave between barriers, stage_B(ct+1)
// overlapped with epilogue(ct) via async global_load_lds. XOR-swizzled LDS
// (chunk (m,c) -> physical c^(m&15)) spreads ds_read_b128 frags across all
// bank groups. NSPLIT=8 -> 512 blocks = exactly 2/CU (LDS 68KB). bf16-S
// numerics validated in R3 (absmax 0.0 vs threshold 4.75e-2).

namespace {

constexpr int Bsz = 8192;
constexpr int Dd  = 128;
constexpr float EPSv = 0.1f;

constexpr int BM = 128, BN = 128;
constexpr int NSPLIT = 8;
constexpr int COLS_PER_SPLIT = Bsz / NSPLIT;       // 1024
constexpr int CT_PER_SPLIT = COLS_PER_SPLIT / BN;  // 8
constexpr int NBLK_M = Bsz / BM;                   // 64

typedef __attribute__((ext_vector_type(8))) short short8;   // 8 bf16 = 4 VGPRs
typedef __attribute__((ext_vector_type(4))) float float4v;  // MFMA C/D

__device__ inline void async_ld16(const void* g, void* l) {
  __builtin_amdgcn_global_load_lds(
      (const __attribute__((address_space(1))) void*)g,
      (__attribute__((address_space(3))) void*)l, 16, 0, 0);
}

// Stage a 128x128 bf16 slab into LDS with XOR swizzle.
// Physical 16B chunk P = i*256+tid holds logical (m=P>>4, c=(P&15)^(m&15)).
// LDS dst is lane-linear (global_load_lds wave-uniform-base requirement).
__device__ inline void stage_slab(const ushort* __restrict__ src, int baserow,
                                  short* __restrict__ dst, int tid) {
#pragma unroll
  for (int i = 0; i < 8; ++i) {
    const int P = i * 256 + tid;
    const int m = P >> 4;
    const int c = (P & 15) ^ (m & 15);
    async_ld16(src + (size_t)(baserow + m) * Dd + c * 8, dst + P * 8);
  }
}

// cast x (fp32) to bf16; also zero the loss accumulators (ws poisoned 0xAA)
__global__ __launch_bounds__(256)
void k_split(const float* __restrict__ x, ushort* __restrict__ xh,
             float* __restrict__ accum) {
  const int i = (blockIdx.x * 256 + threadIdx.x) * 4;
  if (i == 0) { accum[0] = 0.f; accum[1] = 0.f; }
  const float4 v = *reinterpret_cast<const float4*>(x + i);
  const float f[4] = {v.x, v.y, v.z, v.w};
  ushort4 h;
  ushort* hp = &h.x;
#pragma unroll
  for (int r = 0; r < 4; ++r) {
    __hip_bfloat16 hb = __float2bfloat16(f[r]);
    ushort hu;
    __builtin_memcpy(&hu, &hb, 2);
    hp[r] = hu;
  }
  *reinterpret_cast<ushort4*>(xh + i) = h;
}

// PASS=1: out0/out1 = per-split partial min_pos / max_neg.
// PASS=2: in0/in1 = pMin/pMax partials (reduced in prologue);
//         out0/out1 = per-split partial pos_sum / neg_sum (unscaled exps).
template <int PASS>
__global__ __launch_bounds__(256, 2)
void k_gemm(const ushort* __restrict__ xh, const int* __restrict__ y,
            const float* __restrict__ in0, const float* __restrict__ in1,
            float* __restrict__ out0, float* __restrict__ out1) {
  __shared__ __align__(16) short sA[BM * Dd];  // 32 KB
  __shared__ __align__(16) short sB[BN * Dd];  // 32 KB
  __shared__ int yA[BM], yB[BN];
  __shared__ float red0[BM][2], red1[BM][2];
  __shared__ float rlo[BM], rhi[BM];

  const int tid  = threadIdx.x;
  const int lane = tid & 63;
  const int wave = tid >> 6;
  const int wm = wave >> 1, wn = wave & 1;  // 2x2 wave grid, 64x64 each
  const int q   = lane >> 4;                // row-quad / k-chunk selector
  const int c16 = lane & 15;                // col within 16-tile
  const int rowbase = blockIdx.x * BM;
  const int split   = blockIdx.y;
  const int col0    = split * COLS_PER_SPLIT;

  if (tid < BM) {
    yA[tid] = y[rowbase + tid];
    if (PASS == 2) {  // fold former k_thresh: reduce partials for our rows
      float mn = INFINITY, mx = -INFINITY;
#pragma unroll
      for (int s = 0; s < NSPLIT; ++s) {
        mn = fminf(mn, in0[s * Bsz + rowbase + tid]);
        mx = fmaxf(mx, in1[s * Bsz + rowbase + tid]);
      }
      rlo[tid] = mn;
      rhi[tid] = mx;
    }
  }
  if (tid < BN) yB[tid] = y[col0 + tid];

  stage_slab(xh, rowbase, sA, tid);
  stage_slab(xh, col0, sB, tid);

  // register carries across the 8 column tiles
  float a0[4][4], a1[4][4];  // PASS1: mn/mx ; PASS2: psum/nsum
#pragma unroll
  for (int mt = 0; mt < 4; ++mt)
#pragma unroll
    for (int r = 0; r < 4; ++r) {
      a0[mt][r] = (PASS == 1) ? INFINITY : 0.f;
      a1[mt][r] = (PASS == 1) ? -INFINITY : 0.f;
    }

  for (int ct = 0; ct < CT_PER_SPLIT; ++ct) {
    const int colbase = col0 + ct * BN;
    __syncthreads();  // drains stage of sB(ct) (+sA on ct=0), yB(ct)

    float4v acc[4][4];
#pragma unroll
    for (int mt = 0; mt < 4; ++mt)
#pragma unroll
      for (int nt = 0; nt < 4; ++nt) acc[mt][nt] = 0.f;

#pragma unroll
    for (int kk = 0; kk < 4; ++kk) {
      short8 ah[4], bh[4];
#pragma unroll
      for (int t = 0; t < 4; ++t) {
        // logical chunk kk*4+q of row m; physical chunk ^(m&15)=^c16
        const int pc = ((kk << 2) | q) ^ c16;
        ah[t] = *reinterpret_cast<const short8*>(
            sA + (wm * 64 + t * 16 + c16) * Dd + pc * 8);
        bh[t] = *reinterpret_cast<const short8*>(
            sB + (wn * 64 + t * 16 + c16) * Dd + pc * 8);
      }
#pragma unroll
      for (int mt = 0; mt < 4; ++mt)
#pragma unroll
        for (int nt = 0; nt < 4; ++nt)
          acc[mt][nt] = __builtin_amdgcn_mfma_f32_16x16x32_bf16(
              ah[mt], bh[nt], acc[mt][nt], 0, 0, 0);
    }

    // capture labels before yB is overwritten by next stage
    int yy[4];
#pragma unroll
    for (int nt = 0; nt < 4; ++nt) yy[nt] = yB[wn * 64 + nt * 16 + c16];

    if (ct < CT_PER_SPLIT - 1) {
      __syncthreads();  // all waves done reading sB(ct)/yB(ct)
      stage_slab(xh, colbase + BN, sB, tid);        // async; drained at loop top
      if (tid < BN) yB[tid] = y[colbase + BN + tid];
    }

    // epilogue (pure VALU) overlaps the in-flight staging.
    // C/D layout col=lane&15, row=(lane>>4)*4+reg  [m89; R2/R3 absmax 0.0]
#pragma unroll
    for (int mt = 0; mt < 4; ++mt) {
#pragma unroll
      for (int r = 0; r < 4; ++r) {
        const int rloc = wm * 64 + mt * 16 + q * 4 + r;
        const int gi = rowbase + rloc;
        const int yi = yA[rloc];
        if (PASS == 1) {
          float mn = a0[mt][r], mx = a1[mt][r];
#pragma unroll
          for (int nt = 0; nt < 4; ++nt) {
            const int gj = colbase + wn * 64 + nt * 16 + c16;
            const float s = acc[mt][nt][r];
            const bool same = (yi == yy[nt]);
            mn = fminf(mn, (same && gi != gj) ? s : INFINITY);
            mx = fmaxf(mx, same ? -INFINITY : s);
          }
          a0[mt][r] = mn;
          a1[mt][r] = mx;
        } else {
          float psum = a0[mt][r], nsum = a1[mt][r];
          const float rmn = rlo[rloc], rmx = rhi[rloc];
#pragma unroll
          for (int nt = 0; nt < 4; ++nt) {
            const int gj = colbase + wn * 64 + nt * 16 + c16;
            const float s = acc[mt][nt][r];
            const bool same = (yi == yy[nt]);
            // exp(beta*(s-1)) = e^-50 * e^(50 s): accumulate unscaled
            // e^(50 s) (>= e^-50, never 0 -> nsum>0 <=> any neg kept).
            // one transcendental per element: select the argument.
            const float e = __expf(same ? (-2.f * s) : (50.f * s));
            if (!same && (s + EPSv > rmn)) nsum += e;
            if (same && (gi != gj) && (s - EPSv < rmx)) psum += e;
          }
          a0[mt][r] = psum;
          a1[mt][r] = nsum;
        }
      }
    }
  }

  // single cross-lane reduce at block end; (rloc, wn) has a unique writer
#pragma unroll
  for (int mt = 0; mt < 4; ++mt) {
#pragma unroll
    for (int r = 0; r < 4; ++r) {
      float v0 = a0[mt][r], v1 = a1[mt][r];
#pragma unroll
      for (int d = 1; d < 16; d <<= 1) {
        if (PASS == 1) {
          v0 = fminf(v0, __shfl_xor(v0, d, 64));
          v1 = fmaxf(v1, __shfl_xor(v1, d, 64));
        } else {
          v0 += __shfl_xor(v0, d, 64);
          v1 += __shfl_xor(v1, d, 64);
        }
      }
      if (c16 == 0) {
        const int rloc = wm * 64 + mt * 16 + q * 4 + r;
        red0[rloc][wn] = v0;
        red1[rloc][wn] = v1;
      }
    }
  }

  __syncthreads();
  if (tid < BM) {
    const int o = split * Bsz + rowbase + tid;
    if (PASS == 1) {
      out0[o] = fminf(red0[tid][0], red0[tid][1]);
      out1[o] = fmaxf(red1[tid][0], red1[tid][1]);
    } else {
      out0[o] = red0[tid][0] + red0[tid][1];
      out1[o] = red1[tid][0] + red1[tid][1];
    }
  }
}

__global__ __launch_bounds__(256)
void k_rows(const float* __restrict__ pPos, const float* __restrict__ pNeg,
            float* __restrict__ accum) {
  const int r = blockIdx.x * 256 + threadIdx.x;
  float contrib = 0.f, cnt = 0.f;
  {
    float psum = 0.f, nsum = 0.f;
#pragma unroll
    for (int s = 0; s < NSPLIT; ++s) {
      psum += pPos[s * Bsz + r];
      nsum += pNeg[s * Bsz + r];
    }
    if (psum > 0.f && nsum > 0.f) {
      const float E2   = 7.38905609893065f;       // e^{+alpha*lamda}
      const float EM50 = 1.928749847963918e-22f;  // e^{-beta*lamda}
      contrib = 0.5f * log1pf(psum * E2) + 0.02f * log1pf(nsum * EM50);
      cnt = 1.f;
    }
  }
  __shared__ float sb[256], sc[256];
  sb[threadIdx.x] = contrib;
  sc[threadIdx.x] = cnt;
  __syncthreads();
  for (int off = 128; off > 0; off >>= 1) {
    if (threadIdx.x < off) {
      sb[threadIdx.x] += sb[threadIdx.x + off];
      sc[threadIdx.x] += sc[threadIdx.x + off];
    }
    __syncthreads();
  }
  if (threadIdx.x == 0) {
    atomicAdd(&accum[0], sb[0]);
    atomicAdd(&accum[1], sc[0]);
  }
}

__global__ void k_fin(const float* __restrict__ accum, float* __restrict__ out) {
  if (threadIdx.x == 0 && blockIdx.x == 0)
    out[0] = (accum[1] > 0.f) ? accum[0] / accum[1] : 0.f;
}

}  // namespace

extern "C" void kernel_launch(void* const* d_in, const int* in_sizes, int n_in,
                              void* d_out, int out_size, void* d_ws, size_t ws_size,
                              hipStream_t stream) {
  const float* x = (const float*)d_in[0];
  const int*   y = (const int*)d_in[1];
  float* out = (float*)d_out;

  // workspace layout
  ushort* xh  = (ushort*)d_ws;                      // [Bsz*Dd] bf16 (2 MB)
  float* pMin = (float*)(xh + (size_t)Bsz * Dd);    // [NSPLIT][Bsz]
  float* pMax = pMin + NSPLIT * Bsz;
  float* pPos = pMax + NSPLIT * Bsz;
  float* pNeg = pPos + NSPLIT * Bsz;
  float* accum = pNeg + NSPLIT * Bsz;               // [2] (sum, n_valid)

  dim3 blk(256);
  k_split<<<dim3((Bsz * Dd) / (256 * 4)), blk, 0, stream>>>(x, xh, accum);

  dim3 grid(NBLK_M, NSPLIT);
  k_gemm<1><<<grid, blk, 0, stream>>>(xh, y, nullptr, nullptr, pMin, pMax);
  k_gemm<2><<<grid, blk, 0, stream>>>(xh, y, pMin, pMax, pPos, pNeg);
  k_rows<<<dim3(Bsz / 256), blk, 0, stream>>>(pPos, pNeg, accum);
  k_fin<<<1, 64, 0, stream>>>(accum, out);
}